// Round 4
// baseline (10620.496 us; speedup 1.0000x reference)
//
#include <hip/hip_runtime.h>
#include <cstdint>
#include <cstddef>

#define T_SEQ 1024
#define BATCH 64
#define NH 2048
// NINP == 2048 as well

typedef _Float16 half8 __attribute__((ext_vector_type(8)));
typedef _Float16 half4 __attribute__((ext_vector_type(4)));
typedef float f32x4 __attribute__((ext_vector_type(4)));
typedef unsigned u32x2 __attribute__((ext_vector_type(2)));

__device__ inline void gload_lds16(const void* g, void* l) {
    __builtin_amdgcn_global_load_lds(
        (const __attribute__((address_space(1))) uint32_t*)g,
        (__attribute__((address_space(3))) uint32_t*)l,
        16, 0, 0);
}

// LLC-bypass (sc0 sc1) ops: complete at the coherence point (Infinity Cache).
#define LLC_ST2(addr, val)                                                   \
    asm volatile("global_store_short %0, %1, off sc0 sc1"                    \
                 :: "v"(addr), "v"(val) : "memory")
#define LLC_ST4(addr, val)                                                   \
    asm volatile("global_store_dword %0, %1, off sc0 sc1"                    \
                 :: "v"(addr), "v"(val) : "memory")
#define LLC_ST4F(addr, val)                                                  \
    asm volatile("global_store_dword %0, %1, off sc0 sc1"                    \
                 :: "v"(addr), "v"(val) : "memory")
#define LLC_LD8(dst, addr)                                                   \
    asm volatile("global_load_dwordx2 %0, %1, off sc0 sc1\n\ts_waitcnt vmcnt(0)" \
                 : "=v"(dst) : "v"(addr))

// ---------------- fp32 -> fp16 conversion (vectorized, n % 4 == 0) ----------
__global__ __launch_bounds__(256) void cvt_f32_f16(const float* __restrict__ src,
                                                   _Float16* __restrict__ dst,
                                                   long long n) {
    long long i = ((long long)blockIdx.x * 256 + threadIdx.x) * 4;
    long long stride = (long long)gridDim.x * 256 * 4;
    for (; i < n; i += stride) {
        const float4 v = *(const float4*)(src + i);
        half4 o;
        o[0] = (_Float16)v.x; o[1] = (_Float16)v.y;
        o[2] = (_Float16)v.z; o[3] = (_Float16)v.w;
        *(half4*)(dst + i) = o;
    }
}

// ---------------- projection GEMM: C[m][n] = sum_k A[m][k] * B[n][k] --------
// A: [M][2048] fp16, B: [6144][2048] fp16 (Wcx|Wix|Wfx rows), C: [M][6144] fp16
__global__ __launch_bounds__(256) void proj_gemm(const _Float16* __restrict__ A,
                                                 const _Float16* __restrict__ B,
                                                 _Float16* __restrict__ C, int M) {
    __shared__ _Float16 As[128][64];
    __shared__ _Float16 Bs[128][64];
    const int NBN = 48;                 // 6144 / 128
    const int nbm = M >> 7;
    const int nwg = nbm * NBN;          // divisible by 8 (M >= 2048)
    const int per = nwg >> 3;
    const int bid = blockIdx.x;
    const int swz = (bid & 7) * per + (bid >> 3);   // XCD-aware swizzle (bijective)
    const int bm = swz / NBN, bn = swz % NBN;

    const int tid = threadIdx.x;
    const int lane = tid & 63, w = tid >> 6;
    const int wm = w & 1, wn = w >> 1;

    f32x4 acc[4][4] = {};

    const int srow = lane >> 3;         // 0..7
    const int scol = (lane & 7) * 8;    // half units

    for (int bk = 0; bk < NH / 64; ++bk) {
#pragma unroll
        for (int i = 0; i < 4; ++i) {
            int r = w * 32 + i * 8;
            const _Float16* gA = A + (size_t)(bm * 128 + r + srow) * NH + bk * 64 + scol;
            gload_lds16(gA, &As[r][0]);
            const _Float16* gB = B + (size_t)(bn * 128 + r + srow) * NH + bk * 64 + scol;
            gload_lds16(gB, &Bs[r][0]);
        }
        __syncthreads();
#pragma unroll
        for (int kk = 0; kk < 2; ++kk) {
            half8 af[4], bf[4];
#pragma unroll
            for (int mi = 0; mi < 4; ++mi)
                af[mi] = *(const half8*)&As[wm * 64 + mi * 16 + (lane & 15)][kk * 32 + (lane >> 4) * 8];
#pragma unroll
            for (int ni = 0; ni < 4; ++ni)
                bf[ni] = *(const half8*)&Bs[wn * 64 + ni * 16 + (lane & 15)][kk * 32 + (lane >> 4) * 8];
#pragma unroll
            for (int mi = 0; mi < 4; ++mi)
#pragma unroll
                for (int ni = 0; ni < 4; ++ni)
                    acc[mi][ni] = __builtin_amdgcn_mfma_f32_16x16x32_f16(af[mi], bf[ni], acc[mi][ni], 0, 0, 0);
        }
        __syncthreads();
    }
#pragma unroll
    for (int mi = 0; mi < 4; ++mi)
#pragma unroll
        for (int ni = 0; ni < 4; ++ni)
#pragma unroll
            for (int r = 0; r < 4; ++r) {
                int m = bm * 128 + wm * 64 + mi * 16 + (lane >> 4) * 4 + r;
                int n = bn * 128 + wn * 64 + ni * 16 + (lane & 15);
                C[(size_t)m * 6144 + n] = (_Float16)acc[mi][ni][r];
            }
}

// ---------------- persistent scan kernel ------------------------------------
// 256 WGs x 512 threads, 1 WG/CU. Each WG: b-group g (32 rows), j-slice of 16
// cols (XCD-contiguous). Weights (128KB) in LDS. h STORES are sc0sc1
// write-through to the LLC; h LOADS are normal cached loads served by the
// per-XCD L2, made coherent by a per-step agent-acquire fence (buffer_inv sc1,
// a flash invalidate -- L2 holds NO dirty lines: out/flags/h stores all bypass).
// Barrier: per-WG flag stores + wave-0 polls its group's 128 flags.
__global__ __launch_bounds__(512, 1) void scan_kernel(
    const _Float16* __restrict__ proj,   // [nsteps*64][6144] fp16 (c | ix | fx)
    const _Float16* __restrict__ Wr,     // [2][2048][2048] fp16 (W_ih, W_fh)
    _Float16* hb0, _Float16* hb1,        // [64][2048] fp16 ping-pong
    const float* __restrict__ b_i, const float* __restrict__ b_f,
    float* __restrict__ out,             // d_out: [1024][64][2048] + [64][2048]
    unsigned* flags, int t0, int nsteps) {
    extern __shared__ char smem[];
    _Float16* Wlds = (_Float16*)smem;          // 131072 B
    float* red = (float*)(smem + 131072);      // 12288 B: [6 slots][8 regs][64 lanes]

    // XCD-contiguous mapping: wg%8 = XCD (round-robin dispatch); give each XCD
    // 16 contiguous j-slices per group so proj/out 128B lines stay on one XCD.
    const int wg = blockIdx.x;
    const int xcd = wg & 7;
    const int slot = wg >> 3;            // 0..31
    const int g = slot & 1;              // b-group
    const int idx = xcd * 16 + (slot >> 1);   // 0..127, contiguous per XCD
    const int j0 = idx * 16;
    const int b0 = g * 32;
    unsigned* flags_g = flags + g * 256;      // 1KB apart per group

    const int tid = threadIdx.x;
    const int lane = tid & 63;
    const int w = tid >> 6;      // 8 waves
    const int mi = w & 1;        // m-tile (16 rows)
    const int kq = w >> 1;       // k-quarter (512 k)

    // One-time fill of LDS weight fragments:
    // fragment (gate, kk 0..63, lane l) = W[j0 + (l&15)][kk*32 + (l>>4)*8 .. +8]
    for (int q = 0; q < 16; ++q) {
        int e = q * 512 + tid;            // 0..8191
        int l = e & 63;
        int fk = (e >> 6) & 63;
        int gate = e >> 12;
        const _Float16* src = Wr + ((size_t)gate << 22) +
                              (size_t)(j0 + (l & 15)) * NH + fk * 32 + (l >> 4) * 8;
        *(half8*)(Wlds + ((size_t)(gate * 64 + fk) * 64 + l) * 8) = *(const half8*)src;
    }

    const float bi_s = b_i[j0 + (lane & 15)];
    const float bf_s = b_f[j0 + (lane & 15)];

    // h[b][j] carry + first-step proj preload (epilogue waves only).
    float hprev[4], pc[4], pix[4], pfx[4];
    if (kq == 0) {
        const _Float16* hini = (t0 & 1) ? hb1 : hb0;
#pragma unroll
        for (int r = 0; r < 4; ++r) {
            int b = b0 + mi * 16 + (lane >> 4) * 4 + r;
            int j = j0 + (lane & 15);
            unsigned tmp;
            asm volatile("global_load_ushort %0, %1, off sc0 sc1\n\ts_waitcnt vmcnt(0)"
                         : "=v"(tmp) : "v"(hini + (size_t)b * NH + j));
            hprev[r] = (float)__builtin_bit_cast(_Float16, (unsigned short)tmp);
            size_t pbase = ((size_t)b) * 6144 + j;
            pc[r] = (float)proj[pbase];
            pix[r] = (float)proj[pbase + 2048];
            pfx[r] = (float)proj[pbase + 4096];
        }
    }

    __syncthreads();

    for (int s = 0; s < nsteps; ++s) {
        const int t = t0 + s;
        const _Float16* hcur = (t & 1) ? hb1 : hb0;
        _Float16* hnxt = (t & 1) ? hb0 : hb1;

        // A fragments: 16 rows x 512-k quarter, normal cached loads (L2-served;
        // coherence from the pre-step acquire fence). Compiler batches the 16
        // dwordx4 loads and overlaps the LDS weight reads beneath them.
        half8 afr[16];
        const _Float16* hrow = hcur + (size_t)(b0 + mi * 16 + (lane & 15)) * NH +
                               kq * 512 + (lane >> 4) * 8;
#pragma unroll
        for (int u = 0; u < 16; ++u) afr[u] = *(const half8*)(hrow + u * 32);

        f32x4 ai0 = {}, ai1 = {}, af0 = {}, af1 = {};
#pragma unroll
        for (int u = 0; u < 16; ++u) {
            int fk = kq * 16 + u;
            half8 wi = *(const half8*)(Wlds + ((size_t)fk * 64 + lane) * 8);
            half8 wf = *(const half8*)(Wlds + ((size_t)(64 + fk) * 64 + lane) * 8);
            if (u & 1) {
                ai1 = __builtin_amdgcn_mfma_f32_16x16x32_f16(afr[u], wi, ai1, 0, 0, 0);
                af1 = __builtin_amdgcn_mfma_f32_16x16x32_f16(afr[u], wf, af1, 0, 0, 0);
            } else {
                ai0 = __builtin_amdgcn_mfma_f32_16x16x32_f16(afr[u], wi, ai0, 0, 0, 0);
                af0 = __builtin_amdgcn_mfma_f32_16x16x32_f16(afr[u], wf, af0, 0, 0, 0);
            }
        }
        f32x4 acc_i = ai0 + ai1;
        f32x4 acc_f = af0 + af1;

        // k-reduce staging: [slot][reg][lane] layout, lane stride 4B -> no
        // bank conflicts (was 16-way with the f32x4-strided layout).
        if (kq != 0) {
            const int sl = mi * 3 + (kq - 1);
#pragma unroll
            for (int r = 0; r < 4; ++r) {
                red[(sl * 8 + r) * 64 + lane] = acc_i[r];
                red[(sl * 8 + 4 + r) * 64 + lane] = acc_f[r];
            }
        }
        __syncthreads();

        float hn_keep[4];
        if (kq == 0) {
#pragma unroll
            for (int p = 0; p < 3; ++p) {
                const int sl = mi * 3 + p;
#pragma unroll
                for (int r = 0; r < 4; ++r) {
                    acc_i[r] += red[(sl * 8 + r) * 64 + lane];
                    acc_f[r] += red[(sl * 8 + 4 + r) * 64 + lane];
                }
            }
#pragma unroll
            for (int r = 0; r < 4; ++r) {
                int b = b0 + mi * 16 + (lane >> 4) * 4 + r;
                int j = j0 + (lane & 15);
                float iv = 1.0f / (1.0f + __expf(-(acc_i[r] + pix[r] + bi_s)));
                float fv = 1.0f / (1.0f + __expf(-(acc_f[r] + pfx[r] + bf_s)));
                float z = iv * pc[r] + fv * hprev[r];
                float hn = 1.0f - 2.0f / (__expf(2.0f * z) + 1.0f);   // tanh(z)
                hprev[r] = hn;
                hn_keep[r] = hn;
                _Float16 hn16 = (_Float16)hn;
                LLC_ST2(hnxt + (size_t)b * NH + j, hn16);             // -> LLC
            }
        }
        // Drains the h-stores (per-wave vmcnt(0) before s_barrier): once every
        // wave passes, all h values for this WG are complete at the LLC.
        __syncthreads();

        const unsigned tv = (unsigned)(t + 1);
        // Arrive: one flag STORE per WG (distinct addresses -> no RMW serial).
        if (tid == 0) {
            unsigned* myflag = flags_g + idx;
            LLC_ST4(myflag, tv);
        }
        // out-stores (bypass: keep L2 clean for the acquire-inv) + proj
        // prefetch: both complete during the poll window.
        if (kq == 0) {
#pragma unroll
            for (int r = 0; r < 4; ++r) {
                int b = b0 + mi * 16 + (lane >> 4) * 4 + r;
                int j = j0 + (lane & 15);
                float* oaddr = out + (size_t)t * (BATCH * NH) + (size_t)b * NH + j;
                LLC_ST4F(oaddr, hn_keep[r]);
                if (t == T_SEQ - 1) {
                    float* faddr = out + (size_t)T_SEQ * (BATCH * NH) + (size_t)b * NH + j;
                    LLC_ST4F(faddr, hn_keep[r]);
                }
            }
            if (s + 1 < nsteps) {
#pragma unroll
                for (int r = 0; r < 4; ++r) {
                    int b = b0 + mi * 16 + (lane >> 4) * 4 + r;
                    int j = j0 + (lane & 15);
                    size_t pbase = ((size_t)(s + 1) * 64 + b) * 6144 + j;
                    pc[r] = (float)proj[pbase];
                    pix[r] = (float)proj[pbase + 2048];
                    pfx[r] = (float)proj[pbase + 4096];
                }
            }
        }
        // Wave 0 polls all 128 flags of its group (4 cache lines, 2 per lane),
        // then invalidates L1 + this XCD's L2 (clean caches -> flash inv) so
        // the next step's cached h loads refill from the LLC.
        if (w == 0) {
            const unsigned* fb = flags_g + lane * 2;
            while (true) {
                u32x2 v;
                LLC_LD8(v, fb);
                if (__all(v[0] >= tv && v[1] >= tv)) break;
                __builtin_amdgcn_s_sleep(1);
            }
            __builtin_amdgcn_fence(__ATOMIC_ACQUIRE, "agent");
        }
        __syncthreads();
    }
}

// ---------------- host launch -----------------------------------------------
extern "C" void kernel_launch(void* const* d_in, const int* in_sizes, int n_in,
                              void* d_out, int out_size, void* d_ws, size_t ws_size,
                              hipStream_t stream) {
    const float* x = (const float*)d_in[0];
    const float* hidden = (const float*)d_in[1];
    const float* W_cx = (const float*)d_in[2];
    const float* W_ih = (const float*)d_in[3];
    const float* W_ix = (const float*)d_in[4];
    const float* W_fh = (const float*)d_in[5];
    const float* W_fx = (const float*)d_in[6];
    const float* b_i = (const float*)d_in[7];
    const float* b_f = (const float*)d_in[8];
    float* out = (float*)d_out;

    char* ws = (char*)d_ws;
    size_t off = 0;
    auto alloc = [&](size_t bytes) {
        char* p = ws + off;
        off += (bytes + 255) & ~(size_t)255;
        return p;
    };
    _Float16* Wp = (_Float16*)alloc((size_t)6144 * NH * 2);       // 24 MB
    _Float16* Wr = (_Float16*)alloc((size_t)2 * NH * NH * 2);     // 16 MB
    _Float16* hb0 = (_Float16*)alloc((size_t)BATCH * NH * 2);
    _Float16* hb1 = (_Float16*)alloc((size_t)BATCH * NH * 2);
    unsigned* flags = (unsigned*)alloc(4096);
    const size_t fixed = off;

    int chunk = 32;
    for (int c = T_SEQ; c >= 32; c >>= 1) {
        size_t need = fixed + (size_t)c * 64 * NH * 2 + (size_t)c * 64 * 6144 * 2 + 1024;
        if (need <= ws_size) { chunk = c; break; }
    }
    _Float16* xh = (_Float16*)alloc((size_t)chunk * 64 * NH * 2);
    _Float16* proj = (_Float16*)alloc((size_t)chunk * 64 * 6144 * 2);

    hipMemsetAsync(flags, 0, 4096, stream);

    const long long wsz = (long long)NH * NH;
    cvt_f32_f16<<<2048, 256, 0, stream>>>(W_cx, Wp, wsz);
    cvt_f32_f16<<<2048, 256, 0, stream>>>(W_ix, Wp + wsz, wsz);
    cvt_f32_f16<<<2048, 256, 0, stream>>>(W_fx, Wp + 2 * wsz, wsz);
    cvt_f32_f16<<<2048, 256, 0, stream>>>(W_ih, Wr, wsz);
    cvt_f32_f16<<<2048, 256, 0, stream>>>(W_fh, Wr + wsz, wsz);
    cvt_f32_f16<<<128, 256, 0, stream>>>(hidden, hb0, (long long)BATCH * NH);

    const int nch = T_SEQ / chunk;
    for (int c = 0; c < nch; ++c) {
        const int t0 = c * chunk;
        const int M = chunk * 64;
        cvt_f32_f16<<<2048, 256, 0, stream>>>(x + (size_t)t0 * 64 * NH, xh, (long long)M * NH);
        proj_gemm<<<dim3((M / 128) * 48), 256, 0, stream>>>(xh, Wp, proj, M);
        scan_kernel<<<256, 512, 143360, stream>>>(proj, Wr, hb0, hb1, b_i, b_f,
                                                  out, flags, t0, chunk);
    }
}

// Round 6
// 9894.694 us; speedup vs baseline: 1.0734x; 1.0734x over previous
//
#include <hip/hip_runtime.h>
#include <cstdint>
#include <cstddef>

#define T_SEQ 1024
#define BATCH 64
#define NH 2048
// NINP == 2048 as well

typedef _Float16 half8 __attribute__((ext_vector_type(8)));
typedef _Float16 half4 __attribute__((ext_vector_type(4)));
typedef float f32x4 __attribute__((ext_vector_type(4)));
typedef unsigned u32x4 __attribute__((ext_vector_type(4)));

__device__ inline void gload_lds16(const void* g, void* l) {
    __builtin_amdgcn_global_load_lds(
        (const __attribute__((address_space(1))) uint32_t*)g,
        (__attribute__((address_space(3))) uint32_t*)l,
        16, 0, 0);
}

// LLC-bypass (sc0 sc1) ops: complete at the coherence point (Infinity Cache).
#define LLC_LD16NW(dst, addr)                                                \
    asm volatile("global_load_dwordx4 %0, %1, off sc0 sc1"                   \
                 : "=v"(dst) : "v"(addr))
#define LLC_LD4(dst, addr)                                                   \
    asm volatile("global_load_dword %0, %1, off sc0 sc1\n\ts_waitcnt vmcnt(0)" \
                 : "=v"(dst) : "v"(addr))
#define LLC_LD16W(dst, addr)                                                 \
    asm volatile("global_load_dwordx4 %0, %1, off sc0 sc1\n\ts_waitcnt vmcnt(0)" \
                 : "=v"(dst) : "v"(addr))
#define LLC_ST2(addr, val)                                                   \
    asm volatile("global_store_short %0, %1, off sc0 sc1"                    \
                 :: "v"(addr), "v"(val) : "memory")
#define LLC_ST4(addr, val)                                                   \
    asm volatile("global_store_dword %0, %1, off sc0 sc1"                    \
                 :: "v"(addr), "v"(val) : "memory")
#define LLC_ST16(addr, val)                                                  \
    asm volatile("global_store_dwordx4 %0, %1, off sc0 sc1"                  \
                 :: "v"(addr), "v"(val) : "memory")

// Explicit drain: inline-asm VMEM stores are INVISIBLE to hipcc's waitcnt
// insertion, so s_barrier is NOT guaranteed to be preceded by vmcnt(0).
// Every data-store -> flag-store ordering must drain explicitly (r5 bug).
__device__ inline void wait_vm0() {
    asm volatile("s_waitcnt vmcnt(0)" ::: "memory");
}

// ---------------- fp32 -> fp16 conversion (vectorized, n % 4 == 0) ----------
__global__ __launch_bounds__(256) void cvt_f32_f16(const float* __restrict__ src,
                                                   _Float16* __restrict__ dst,
                                                   long long n) {
    long long i = ((long long)blockIdx.x * 256 + threadIdx.x) * 4;
    long long stride = (long long)gridDim.x * 256 * 4;
    for (; i < n; i += stride) {
        const float4 v = *(const float4*)(src + i);
        half4 o;
        o[0] = (_Float16)v.x; o[1] = (_Float16)v.y;
        o[2] = (_Float16)v.z; o[3] = (_Float16)v.w;
        *(half4*)(dst + i) = o;
    }
}

// ---------------- projection GEMM: C[m][n] = sum_k A[m][k] * B[n][k] --------
// A: [M][2048] fp16, B: [6144][2048] fp16 (Wcx|Wix|Wfx rows), C: [M][6144] fp16
__global__ __launch_bounds__(256) void proj_gemm(const _Float16* __restrict__ A,
                                                 const _Float16* __restrict__ B,
                                                 _Float16* __restrict__ C, int M) {
    __shared__ _Float16 As[128][64];
    __shared__ _Float16 Bs[128][64];
    const int NBN = 48;                 // 6144 / 128
    const int nbm = M >> 7;
    const int nwg = nbm * NBN;          // divisible by 8 (M >= 2048)
    const int per = nwg >> 3;
    const int bid = blockIdx.x;
    const int swz = (bid & 7) * per + (bid >> 3);   // XCD-aware swizzle (bijective)
    const int bm = swz / NBN, bn = swz % NBN;

    const int tid = threadIdx.x;
    const int lane = tid & 63, w = tid >> 6;
    const int wm = w & 1, wn = w >> 1;

    f32x4 acc[4][4] = {};

    const int srow = lane >> 3;         // 0..7
    const int scol = (lane & 7) * 8;    // half units

    for (int bk = 0; bk < NH / 64; ++bk) {
#pragma unroll
        for (int i = 0; i < 4; ++i) {
            int r = w * 32 + i * 8;
            const _Float16* gA = A + (size_t)(bm * 128 + r + srow) * NH + bk * 64 + scol;
            gload_lds16(gA, &As[r][0]);
            const _Float16* gB = B + (size_t)(bn * 128 + r + srow) * NH + bk * 64 + scol;
            gload_lds16(gB, &Bs[r][0]);
        }
        __syncthreads();
#pragma unroll
        for (int kk = 0; kk < 2; ++kk) {
            half8 af[4], bf[4];
#pragma unroll
            for (int mi = 0; mi < 4; ++mi)
                af[mi] = *(const half8*)&As[wm * 64 + mi * 16 + (lane & 15)][kk * 32 + (lane >> 4) * 8];
#pragma unroll
            for (int ni = 0; ni < 4; ++ni)
                bf[ni] = *(const half8*)&Bs[wn * 64 + ni * 16 + (lane & 15)][kk * 32 + (lane >> 4) * 8];
#pragma unroll
            for (int mi = 0; mi < 4; ++mi)
#pragma unroll
                for (int ni = 0; ni < 4; ++ni)
                    acc[mi][ni] = __builtin_amdgcn_mfma_f32_16x16x32_f16(af[mi], bf[ni], acc[mi][ni], 0, 0, 0);
        }
        __syncthreads();
    }
#pragma unroll
    for (int mi = 0; mi < 4; ++mi)
#pragma unroll
        for (int ni = 0; ni < 4; ++ni)
#pragma unroll
            for (int r = 0; r < 4; ++r) {
                int m = bm * 128 + wm * 64 + mi * 16 + (lane >> 4) * 4 + r;
                int n = bn * 128 + wn * 64 + ni * 16 + (lane & 15);
                C[(size_t)m * 6144 + n] = (_Float16)acc[mi][ni][r];
            }
}

// ---------------- persistent scan kernel (j x k decomposition) --------------
// 256 WGs x 512 thr, 1 WG/CU. WG = (group g of 32 b-rows, j-slice of 64 cols,
// k-slice of 512 k). LDS: 128KB weights (2 gates x 64 j x 512 k, MFMA B-frag
// order) + 32KB h-stage (shared A-operand, XOR-swizzled). Per step:
//  all WGs: poll hflags(own k-range) -> stage h[32x512] -> GEMM (32 MFMA/wave)
//  ks!=0:  store fp32 partial (bypass) + DRAIN + barrier + pflag
//  ks==0:  poll 3 pflags, load partials, reduce, epilogue (h carried in regs),
//          store h (bypass fp16) + DRAIN + barrier + hflag; out/proj off-path.
// All cross-WG data moves via LLC-bypass (sc0 sc1); no cache maintenance ops.
__global__ __launch_bounds__(512, 1) void scan_kernel(
    const _Float16* __restrict__ proj,   // [nsteps*64][6144] fp16 (c | ix | fx)
    const _Float16* __restrict__ Wr,     // [2][2048][2048] fp16 (W_ih, W_fh)
    _Float16* hb0, _Float16* hb1,        // [64][2048] fp16 ping-pong
    const float* __restrict__ b_i, const float* __restrict__ b_f,
    float* __restrict__ out,             // d_out: [1024][64][2048] + [64][2048]
    unsigned* hflags, unsigned* pflags, float* part,
    int t0, int nsteps) {
    extern __shared__ char smem[];
    _Float16* Wlds = (_Float16*)smem;          // 131072 B
    char* hstage = smem + 131072;              // 32768 B: [32 rows][1KB, swizzled]

    const int wg = blockIdx.x;
    const int xcd = wg & 7;
    const int slot = wg >> 3;            // 0..31
    const int g = slot & 1;              // b-group
    const int rem = slot >> 1;           // 0..15
    const int js = xcd * 4 + (rem & 3);  // 0..31 (XCD-contiguous j-slices)
    const int ks = rem >> 2;             // 0..3
    const int j0g = js * 64;
    const int b0 = g * 32;
    const int k0 = ks * 512;

    const int tid = threadIdx.x;
    const int lane = tid & 63;
    const int w = tid >> 6;              // 8 waves
    const int mi = w & 1;                // m-tile (16 b-rows)
    const int nt = w >> 1;               // n-tile (16 j-cols)

    unsigned* hflags_g = hflags + g * 32;       // [32]
    unsigned* pflags_g = pflags + g * 128;      // [32][4] (3 used)

    // One-time weight fill: frag(gate, nt, u, lane) =
    //   W[j0g + nt*16 + (lane&15)][k0 + u*32 + (lane>>4)*8 ..+8]
    for (int q = 0; q < 16; ++q) {
        int e = q * 512 + tid;           // 0..8191
        int le = e & 63;
        int u = (e >> 6) & 15;
        int nte = (e >> 10) & 3;
        int gate = e >> 12;
        const _Float16* src = Wr + ((size_t)gate << 22) +
            (size_t)(j0g + nte * 16 + (le & 15)) * NH + k0 + u * 32 + (le >> 4) * 8;
        *(half8*)(Wlds + (((size_t)(gate * 4 + nte) * 16 + u) * 64 + le) * 8) =
            *(const half8*)src;
    }

    const int jj = j0g + nt * 16 + (lane & 15);  // this lane's j column
    const float bi_s = b_i[jj];
    const float bf_s = b_f[jj];

    // Owner state: h carry + first-step proj preload.
    float hprev[4], pc[4], pix[4], pfx[4];
    if (ks == 0) {
        const _Float16* hini = (t0 & 1) ? hb1 : hb0;
#pragma unroll
        for (int r = 0; r < 4; ++r) {
            int b = b0 + mi * 16 + (lane >> 4) * 4 + r;
            unsigned tmp;
            asm volatile("global_load_ushort %0, %1, off sc0 sc1\n\ts_waitcnt vmcnt(0)"
                         : "=v"(tmp) : "v"(hini + (size_t)b * NH + jj));
            hprev[r] = (float)__builtin_bit_cast(_Float16, (unsigned short)tmp);
            size_t pbase = (size_t)b * 6144 + jj;
            pc[r] = (float)proj[pbase];
            pix[r] = (float)proj[pbase + 2048];
            pfx[r] = (float)proj[pbase + 4096];
        }
    }

    __syncthreads();

    for (int s = 0; s < nsteps; ++s) {
        const int t = t0 + s;
        const _Float16* hcur = (t & 1) ? hb1 : hb0;
        _Float16* hnxt = (t & 1) ? hb0 : hb1;
        const unsigned tv = (unsigned)t;          // h_t certificate value

        // 1. wait for h_t of our k-range (8 j-slice flags; value >= t).
        if (w == 0) {
            const unsigned* fa = hflags_g + ks * 8 + (lane & 7);
            while (true) {
                unsigned v;
                LLC_LD4(v, fa);
                if (__all((int)(v >= tv))) break;
                __builtin_amdgcn_s_sleep(1);
            }
        }
        __syncthreads();

        // 2. stage h[32 rows][512 k] into LDS (wave w: rows 4w..4w+3).
        {
            half8 t0v, t1v, t2v, t3v;
            const _Float16* srcb = hcur + (size_t)(b0 + w * 4) * NH + k0 + lane * 8;
            LLC_LD16NW(t0v, srcb);
            LLC_LD16NW(t1v, srcb + NH);
            LLC_LD16NW(t2v, srcb + 2 * NH);
            LLC_LD16NW(t3v, srcb + 3 * NH);
            wait_vm0();
            __builtin_amdgcn_sched_barrier(0);
            const int r0 = w * 4;
            *(half8*)(hstage + (r0 + 0) * 1024 + ((lane * 16) ^ (((r0 + 0) & 7) << 4))) = t0v;
            *(half8*)(hstage + (r0 + 1) * 1024 + ((lane * 16) ^ (((r0 + 1) & 7) << 4))) = t1v;
            *(half8*)(hstage + (r0 + 2) * 1024 + ((lane * 16) ^ (((r0 + 2) & 7) << 4))) = t2v;
            *(half8*)(hstage + (r0 + 3) * 1024 + ((lane * 16) ^ (((r0 + 3) & 7) << 4))) = t3v;
        }
        __syncthreads();

        // 3. GEMM: wave (mi, nt): C[16x16] over K=512, both gates.
        f32x4 ci = {}, cf = {};
        {
            const int arow = mi * 16 + (lane & 15);
            const char* abase = hstage + arow * 1024;
            const int axor = (arow & 7) << 4;
            const _Float16* wbi = Wlds + (((size_t)(0 * 4 + nt) * 16) * 64 + lane) * 8;
            const _Float16* wbf = Wlds + (((size_t)(1 * 4 + nt) * 16) * 64 + lane) * 8;
#pragma unroll
            for (int u = 0; u < 16; ++u) {
                half8 a = *(const half8*)(abase + ((u * 64 + (lane >> 4) * 16) ^ axor));
                half8 wi = *(const half8*)(wbi + (size_t)u * 512);
                half8 wf = *(const half8*)(wbf + (size_t)u * 512);
                ci = __builtin_amdgcn_mfma_f32_16x16x32_f16(a, wi, ci, 0, 0, 0);
                cf = __builtin_amdgcn_mfma_f32_16x16x32_f16(a, wf, cf, 0, 0, 0);
            }
        }

        if (ks != 0) {
            // 4a. store partial (bypass) + DRAIN + barrier + pflag.
            const int slotp = (((t & 1) * 2 + g) * 32 + js) * 3 + (ks - 1);
            float* pb = part + (size_t)slotp * 4096 + w * 512 + lane * 4;
            LLC_ST16(pb, ci);
            LLC_ST16(pb + 256, cf);
            wait_vm0();        // r5 bug fix: drain asm stores before barrier
            __syncthreads();   // now ALL waves' partials are complete at LLC
            if (tid == 0) LLC_ST4(pflags_g + js * 4 + (ks - 1), (unsigned)(t + 1));
        } else {
            // 4b. owner: wait the 3 partials.
            if (w == 0) {
                const unsigned* pf = pflags_g + js * 4;   // 16B aligned
                while (true) {
                    u32x4 v;
                    LLC_LD16W(v, pf);
                    if (__all((int)(v[0] >= tv + 1 && v[1] >= tv + 1 && v[2] >= tv + 1)))
                        break;
                    __builtin_amdgcn_s_sleep(1);
                }
            }
            __syncthreads();

            f32x4 pi0, pg0, pi1, pg1, pi2, pg2;
            const int sbase = (((t & 1) * 2 + g) * 32 + js) * 3;
            const float* pb0 = part + (size_t)(sbase + 0) * 4096 + w * 512 + lane * 4;
            const float* pb1 = part + (size_t)(sbase + 1) * 4096 + w * 512 + lane * 4;
            const float* pb2 = part + (size_t)(sbase + 2) * 4096 + w * 512 + lane * 4;
            LLC_LD16NW(pi0, pb0);
            LLC_LD16NW(pg0, pb0 + 256);
            LLC_LD16NW(pi1, pb1);
            LLC_LD16NW(pg1, pb1 + 256);
            LLC_LD16NW(pi2, pb2);
            LLC_LD16NW(pg2, pb2 + 256);
            wait_vm0();
            __builtin_amdgcn_sched_barrier(0);
            ci += pi0 + pi1 + pi2;
            cf += pg0 + pg1 + pg2;

            float hn_keep[4];
#pragma unroll
            for (int r = 0; r < 4; ++r) {
                int b = b0 + mi * 16 + (lane >> 4) * 4 + r;
                float iv = 1.0f / (1.0f + __expf(-(ci[r] + pix[r] + bi_s)));
                float fv = 1.0f / (1.0f + __expf(-(cf[r] + pfx[r] + bf_s)));
                float z = iv * pc[r] + fv * hprev[r];
                float hn = 1.0f - 2.0f / (__expf(2.0f * z) + 1.0f);   // tanh(z)
                hprev[r] = hn;
                hn_keep[r] = hn;
                _Float16 hn16 = (_Float16)hn;
                LLC_ST2(hnxt + (size_t)b * NH + jj, hn16);            // -> LLC
            }
            wait_vm0();        // r5 bug fix: drain h stores before barrier
            __syncthreads();   // all owner waves' h values complete at LLC
            if (tid == 0) LLC_ST4(hflags_g + js, (unsigned)(t + 1));

            // Off-critical-path: out stores (normal, fire-and-forget) + proj
            // prefetch for next step.
#pragma unroll
            for (int r = 0; r < 4; ++r) {
                int b = b0 + mi * 16 + (lane >> 4) * 4 + r;
                out[(size_t)t * (BATCH * NH) + (size_t)b * NH + jj] = hn_keep[r];
                if (t == T_SEQ - 1)
                    out[(size_t)T_SEQ * (BATCH * NH) + (size_t)b * NH + jj] = hn_keep[r];
            }
            if (s + 1 < nsteps) {
#pragma unroll
                for (int r = 0; r < 4; ++r) {
                    int b = b0 + mi * 16 + (lane >> 4) * 4 + r;
                    size_t pbase = ((size_t)(s + 1) * 64 + b) * 6144 + jj;
                    pc[r] = (float)proj[pbase];
                    pix[r] = (float)proj[pbase + 2048];
                    pfx[r] = (float)proj[pbase + 4096];
                }
            }
        }
    }
}

// ---------------- host launch -----------------------------------------------
extern "C" void kernel_launch(void* const* d_in, const int* in_sizes, int n_in,
                              void* d_out, int out_size, void* d_ws, size_t ws_size,
                              hipStream_t stream) {
    const float* x = (const float*)d_in[0];
    const float* hidden = (const float*)d_in[1];
    const float* W_cx = (const float*)d_in[2];
    const float* W_ih = (const float*)d_in[3];
    const float* W_ix = (const float*)d_in[4];
    const float* W_fh = (const float*)d_in[5];
    const float* W_fx = (const float*)d_in[6];
    const float* b_i = (const float*)d_in[7];
    const float* b_f = (const float*)d_in[8];
    float* out = (float*)d_out;

    char* ws = (char*)d_ws;
    size_t off = 0;
    auto alloc = [&](size_t bytes) {
        char* p = ws + off;
        off += (bytes + 255) & ~(size_t)255;
        return p;
    };
    _Float16* Wp = (_Float16*)alloc((size_t)6144 * NH * 2);       // 24 MB
    _Float16* Wr = (_Float16*)alloc((size_t)2 * NH * NH * 2);     // 16 MB
    _Float16* hb0 = (_Float16*)alloc((size_t)BATCH * NH * 2);
    _Float16* hb1 = (_Float16*)alloc((size_t)BATCH * NH * 2);
    unsigned* hflags = (unsigned*)alloc(256);
    unsigned* pflags = (unsigned*)alloc(1024);
    float* part = (float*)alloc((size_t)2 * 2 * 32 * 3 * 4096 * 4);  // 6 MB
    const size_t fixed = off;

    int chunk = 32;
    for (int c = T_SEQ; c >= 32; c >>= 1) {
        size_t need = fixed + (size_t)c * 64 * NH * 2 + (size_t)c * 64 * 6144 * 2 + 1024;
        if (need <= ws_size) { chunk = c; break; }
    }
    _Float16* xh = (_Float16*)alloc((size_t)chunk * 64 * NH * 2);
    _Float16* proj = (_Float16*)alloc((size_t)chunk * 64 * 6144 * 2);

    hipMemsetAsync(hflags, 0, 256, stream);
    hipMemsetAsync(pflags, 0, 1024, stream);

    const long long wsz = (long long)NH * NH;
    cvt_f32_f16<<<2048, 256, 0, stream>>>(W_cx, Wp, wsz);
    cvt_f32_f16<<<2048, 256, 0, stream>>>(W_ix, Wp + wsz, wsz);
    cvt_f32_f16<<<2048, 256, 0, stream>>>(W_fx, Wp + 2 * wsz, wsz);
    cvt_f32_f16<<<2048, 256, 0, stream>>>(W_ih, Wr, wsz);
    cvt_f32_f16<<<2048, 256, 0, stream>>>(W_fh, Wr + wsz, wsz);
    cvt_f32_f16<<<128, 256, 0, stream>>>(hidden, hb0, (long long)BATCH * NH);

    const int nch = T_SEQ / chunk;
    for (int c = 0; c < nch; ++c) {
        const int t0 = c * chunk;
        const int M = chunk * 64;
        cvt_f32_f16<<<2048, 256, 0, stream>>>(x + (size_t)t0 * 64 * NH, xh, (long long)M * NH);
        proj_gemm<<<dim3((M / 128) * 48), 256, 0, stream>>>(xh, Wp, proj, M);
        scan_kernel<<<256, 512, 163840, stream>>>(proj, Wr, hb0, hb1, b_i, b_f,
                                                  out, hflags, pflags, part, t0, chunk);
    }
}

// Round 8
// 9870.454 us; speedup vs baseline: 1.0760x; 1.0025x over previous
//
#include <hip/hip_runtime.h>
#include <cstdint>
#include <cstddef>

#define T_SEQ 1024
#define BATCH 64
#define NH 2048
// NINP == 2048 as well

typedef _Float16 half8 __attribute__((ext_vector_type(8)));
typedef _Float16 half4 __attribute__((ext_vector_type(4)));
typedef float f32x4 __attribute__((ext_vector_type(4)));
typedef unsigned u32x4 __attribute__((ext_vector_type(4)));

__device__ inline void gload_lds16(const void* g, void* l) {
    __builtin_amdgcn_global_load_lds(
        (const __attribute__((address_space(1))) uint32_t*)g,
        (__attribute__((address_space(3))) uint32_t*)l,
        16, 0, 0);
}

// ---- LLC-scope (sc0 sc1) ops: complete at the coherence point (MALL). -----
#define LLC_LD16NW(dst, addr)                                                \
    asm volatile("global_load_dwordx4 %0, %1, off sc0 sc1"                   \
                 : "=v"(dst) : "v"(addr))
#define LLC_LD4(dst, addr)                                                   \
    asm volatile("global_load_dword %0, %1, off sc0 sc1\n\ts_waitcnt vmcnt(0)" \
                 : "=v"(dst) : "v"(addr))
#define LLC_ST2(addr, val)                                                   \
    asm volatile("global_store_short %0, %1, off sc0 sc1"                    \
                 :: "v"(addr), "v"(val) : "memory")
#define LLC_ST4(addr, val)                                                   \
    asm volatile("global_store_dword %0, %1, off sc0 sc1"                    \
                 :: "v"(addr), "v"(val) : "memory")
#define LLC_ST16(addr, val)                                                  \
    asm volatile("global_store_dwordx4 %0, %1, off sc0 sc1"                  \
                 :: "v"(addr), "v"(val) : "memory")

// Explicit drain: inline-asm VMEM ops are INVISIBLE to hipcc's waitcnt
// insertion (r5 lesson). Every asm-store -> flag ordering drains explicitly,
// and every asm-load use is fenced with sched_barrier(0) (rule #18).
__device__ inline void wait_vm0() {
    asm volatile("s_waitcnt vmcnt(0)" ::: "memory");
}

#define CANARY32 0xFFFFFFFFu   // two fp16 NaNs; unproducible by the arithmetic

// ---------------- fp32 -> fp16 conversion (vectorized, n % 4 == 0) ----------
__global__ __launch_bounds__(256) void cvt_f32_f16(const float* __restrict__ src,
                                                   _Float16* __restrict__ dst,
                                                   long long n) {
    long long i = ((long long)blockIdx.x * 256 + threadIdx.x) * 4;
    long long stride = (long long)gridDim.x * 256 * 4;
    for (; i < n; i += stride) {
        const float4 v = *(const float4*)(src + i);
        half4 o;
        o[0] = (_Float16)v.x; o[1] = (_Float16)v.y;
        o[2] = (_Float16)v.z; o[3] = (_Float16)v.w;
        *(half4*)(dst + i) = o;
    }
}

// ---------------- projection GEMM: C[m][n] = sum_k A[m][k] * B[n][k] --------
// A: [M][2048] fp16, B: [6144][2048] fp16 (Wcx|Wix|Wfx rows), C: [M][6144] fp16
__global__ __launch_bounds__(256) void proj_gemm(const _Float16* __restrict__ A,
                                                 const _Float16* __restrict__ B,
                                                 _Float16* __restrict__ C, int M) {
    __shared__ _Float16 As[128][64];
    __shared__ _Float16 Bs[128][64];
    const int NBN = 48;                 // 6144 / 128
    const int nbm = M >> 7;
    const int nwg = nbm * NBN;          // divisible by 8 (M >= 2048)
    const int per = nwg >> 3;
    const int bid = blockIdx.x;
    const int swz = (bid & 7) * per + (bid >> 3);   // XCD-aware swizzle (bijective)
    const int bm = swz / NBN, bn = swz % NBN;

    const int tid = threadIdx.x;
    const int lane = tid & 63, w = tid >> 6;
    const int wm = w & 1, wn = w >> 1;

    f32x4 acc[4][4] = {};

    const int srow = lane >> 3;         // 0..7
    const int scol = (lane & 7) * 8;    // half units

    for (int bk = 0; bk < NH / 64; ++bk) {
#pragma unroll
        for (int i = 0; i < 4; ++i) {
            int r = w * 32 + i * 8;
            const _Float16* gA = A + (size_t)(bm * 128 + r + srow) * NH + bk * 64 + scol;
            gload_lds16(gA, &As[r][0]);
            const _Float16* gB = B + (size_t)(bn * 128 + r + srow) * NH + bk * 64 + scol;
            gload_lds16(gB, &Bs[r][0]);
        }
        __syncthreads();
#pragma unroll
        for (int kk = 0; kk < 2; ++kk) {
            half8 af[4], bf[4];
#pragma unroll
            for (int mi = 0; mi < 4; ++mi)
                af[mi] = *(const half8*)&As[wm * 64 + mi * 16 + (lane & 15)][kk * 32 + (lane >> 4) * 8];
#pragma unroll
            for (int ni = 0; ni < 4; ++ni)
                bf[ni] = *(const half8*)&Bs[wn * 64 + ni * 16 + (lane & 15)][kk * 32 + (lane >> 4) * 8];
#pragma unroll
            for (int mi = 0; mi < 4; ++mi)
#pragma unroll
                for (int ni = 0; ni < 4; ++ni)
                    acc[mi][ni] = __builtin_amdgcn_mfma_f32_16x16x32_f16(af[mi], bf[ni], acc[mi][ni], 0, 0, 0);
        }
        __syncthreads();
    }
#pragma unroll
    for (int mi = 0; mi < 4; ++mi)
#pragma unroll
        for (int ni = 0; ni < 4; ++ni)
#pragma unroll
            for (int r = 0; r < 4; ++r) {
                int m = bm * 128 + wm * 64 + mi * 16 + (lane >> 4) * 4 + r;
                int n = bn * 128 + wn * 64 + ni * 16 + (lane & 15);
                C[(size_t)m * 6144 + n] = (_Float16)acc[mi][ni][r];
            }
}

// ---------------- persistent scan kernel (j x k, canary partials) -----------
// 256 WGs x 512 thr, 1 WG/CU. Roles from blockIdx (r6-verified mapping). Per
// step: poll hflags(k-range) -> stage h[32x512] in LDS -> GEMM. Writers pack
// their 8 fp32 partials into ONE 16B fp16 store (tear-free) -- the data IS the
// flag: owners poll the slots against fp16-NaN canaries (memset 0xFF), unpack,
// re-arm canary, reduce, epilogue, publish h + hflag. All cross-WG traffic at
// LLC scope (sc0 sc1): zero placement assumptions, no cache maintenance.
__global__ __launch_bounds__(512, 1) void scan_kernel(
    const _Float16* __restrict__ proj,   // [nsteps*64][6144] fp16 (c | ix | fx)
    const _Float16* __restrict__ Wr,     // [2][2048][2048] fp16 (W_ih, W_fh)
    _Float16* hb0, _Float16* hb1,        // [64][2048] fp16 ping-pong
    const float* __restrict__ b_i, const float* __restrict__ b_f,
    float* __restrict__ out,             // d_out: [1024][64][2048] + [64][2048]
    unsigned* hflags, _Float16* part,
    int t0, int nsteps) {
    extern __shared__ char smem[];
    _Float16* Wlds = (_Float16*)smem;          // 131072 B
    char* hstage = smem + 131072;              // 32768 B: [32 rows][1KB, swizzled]

    const int wg = blockIdx.x;
    const int xcd = wg & 7;
    const int slot = wg >> 3;            // 0..31
    const int g = slot & 1;              // b-group
    const int rem = slot >> 1;           // 0..15
    const int js = xcd * 4 + (rem & 3);  // 0..31 (XCD-contiguous j-slices)
    const int ks = rem >> 2;             // 0..3
    const int j0g = js * 64;
    const int b0 = g * 32;
    const int k0 = ks * 512;

    const int tid = threadIdx.x;
    const int lane = tid & 63;
    const int w = tid >> 6;              // 8 waves
    const int mi = w & 1;                // m-tile (16 b-rows)
    const int nt = w >> 1;               // n-tile (16 j-cols)

    unsigned* hflags_g = hflags + g * 32;       // [32], LLC scope

    // One-time weight fill: frag(gate, nt, u, lane) =
    //   W[j0g + nt*16 + (lane&15)][k0 + u*32 + (lane>>4)*8 ..+8]
    for (int q = 0; q < 16; ++q) {
        int e = q * 512 + tid;           // 0..8191
        int le = e & 63;
        int u = (e >> 6) & 15;
        int nte = (e >> 10) & 3;
        int gate = e >> 12;
        const _Float16* src = Wr + ((size_t)gate << 22) +
            (size_t)(j0g + nte * 16 + (le & 15)) * NH + k0 + u * 32 + (le >> 4) * 8;
        *(half8*)(Wlds + (((size_t)(gate * 4 + nte) * 16 + u) * 64 + le) * 8) =
            *(const half8*)src;
    }

    const int jj = j0g + nt * 16 + (lane & 15);  // this lane's j column
    const float bi_s = b_i[jj];
    const float bf_s = b_f[jj];

    // Owner state: h carry + first-step proj preload.
    float hprev[4], pc[4], pix[4], pfx[4];
    if (ks == 0) {
        const _Float16* hini = (t0 & 1) ? hb1 : hb0;
#pragma unroll
        for (int r = 0; r < 4; ++r) {
            int b = b0 + mi * 16 + (lane >> 4) * 4 + r;
            unsigned tmp;
            asm volatile("global_load_ushort %0, %1, off sc0 sc1\n\ts_waitcnt vmcnt(0)"
                         : "=v"(tmp) : "v"(hini + (size_t)b * NH + jj));
            hprev[r] = (float)__builtin_bit_cast(_Float16, (unsigned short)tmp);
            size_t pbase = (size_t)b * 6144 + jj;
            pc[r] = (float)proj[pbase];
            pix[r] = (float)proj[pbase + 2048];
            pfx[r] = (float)proj[pbase + 4096];
        }
    }

    __syncthreads();

    for (int s = 0; s < nsteps; ++s) {
        const int t = t0 + s;
        const _Float16* hcur = (t & 1) ? hb1 : hb0;
        _Float16* hnxt = (t & 1) ? hb0 : hb1;
        const unsigned tv = (unsigned)t;          // h_t certificate value

        // 1. wave 0 polls hflags of our k-range (8 j-slice flags; value >= t).
        if (w == 0) {
            const unsigned* fa = hflags_g + ks * 8 + (lane & 7);
            while (true) {
                unsigned v;
                LLC_LD4(v, fa);
                if (__all((int)(v >= tv))) break;
                __builtin_amdgcn_s_sleep(1);
            }
        }
        __syncthreads();   // also protects hstage WAR (all waves past GEMM(s-1))

        // 2. stage h[32 rows][512 k] into LDS (wave w: rows 4w..4w+3).
        {
            half8 t0v, t1v, t2v, t3v;
            const _Float16* srcb = hcur + (size_t)(b0 + w * 4) * NH + k0 + lane * 8;
            LLC_LD16NW(t0v, srcb);
            LLC_LD16NW(t1v, srcb + NH);
            LLC_LD16NW(t2v, srcb + 2 * NH);
            LLC_LD16NW(t3v, srcb + 3 * NH);
            wait_vm0();
            __builtin_amdgcn_sched_barrier(0);
            const int r0 = w * 4;
            *(half8*)(hstage + (r0 + 0) * 1024 + ((lane * 16) ^ (((r0 + 0) & 7) << 4))) = t0v;
            *(half8*)(hstage + (r0 + 1) * 1024 + ((lane * 16) ^ (((r0 + 1) & 7) << 4))) = t1v;
            *(half8*)(hstage + (r0 + 2) * 1024 + ((lane * 16) ^ (((r0 + 2) & 7) << 4))) = t2v;
            *(half8*)(hstage + (r0 + 3) * 1024 + ((lane * 16) ^ (((r0 + 3) & 7) << 4))) = t3v;
        }
        __syncthreads();

        // 3. GEMM: wave (mi, nt): C[16x16] over K=512, both gates.
        f32x4 ci = {}, cf = {};
        {
            const int arow = mi * 16 + (lane & 15);
            const char* abase = hstage + arow * 1024;
            const int axor = (arow & 7) << 4;
            const _Float16* wbi = Wlds + (((size_t)(0 * 4 + nt) * 16) * 64 + lane) * 8;
            const _Float16* wbf = Wlds + (((size_t)(1 * 4 + nt) * 16) * 64 + lane) * 8;
#pragma unroll
            for (int u = 0; u < 16; ++u) {
                half8 a = *(const half8*)(abase + ((u * 64 + (lane >> 4) * 16) ^ axor));
                half8 wi = *(const half8*)(wbi + (size_t)u * 512);
                half8 wf = *(const half8*)(wbf + (size_t)u * 512);
                ci = __builtin_amdgcn_mfma_f32_16x16x32_f16(a, wi, ci, 0, 0, 0);
                cf = __builtin_amdgcn_mfma_f32_16x16x32_f16(a, wf, cf, 0, 0, 0);
            }
        }

        // part slot layout: [parity][g][js][kw(3)][wave(8)][lane*8 halves]
        const size_t tilebase = (size_t)(((t & 1) * 2 + g) * 32 + js) * 3;

        if (ks != 0) {
            // 4a. writer: pack 8 fp32 -> 8 fp16, ONE 16B store. Data IS flag.
            half8 pk;
#pragma unroll
            for (int r = 0; r < 4; ++r) {
                pk[r] = (_Float16)ci[r];
                pk[4 + r] = (_Float16)cf[r];
            }
            _Float16* pb = part + ((tilebase + (ks - 1)) * 8 + w) * 512 + lane * 8;
            LLC_ST16(pb, pk);
            // no drain, no barrier, no flag: owner polls the data itself.
        } else {
            // 4b. owner: poll the 3 packed slots for this wave against canary.
            _Float16* s0 = part + ((tilebase + 0) * 8 + w) * 512 + lane * 8;
            _Float16* s1 = part + ((tilebase + 1) * 8 + w) * 512 + lane * 8;
            _Float16* s2 = part + ((tilebase + 2) * 8 + w) * 512 + lane * 8;
            u32x4 q0, q1, q2;
            while (true) {
                LLC_LD16NW(q0, s0);
                LLC_LD16NW(q1, s1);
                LLC_LD16NW(q2, s2);
                wait_vm0();
                __builtin_amdgcn_sched_barrier(0);   // rule #18: compare after wait
                bool ok = (q0[0] != CANARY32) && (q1[0] != CANARY32) && (q2[0] != CANARY32);
                if (__all(ok)) break;
                __builtin_amdgcn_s_sleep(1);
            }
            __builtin_amdgcn_sched_barrier(0);
            // re-arm canaries (drained below, before the hflag publish).
            u32x4 can;
            can[0] = CANARY32; can[1] = CANARY32; can[2] = CANARY32; can[3] = CANARY32;
            LLC_ST16(s0, can);
            LLC_ST16(s1, can);
            LLC_ST16(s2, can);

            half8 p0 = __builtin_bit_cast(half8, q0);
            half8 p1 = __builtin_bit_cast(half8, q1);
            half8 p2 = __builtin_bit_cast(half8, q2);
#pragma unroll
            for (int r = 0; r < 4; ++r) {
                ci[r] += (float)p0[r] + (float)p1[r] + (float)p2[r];
                cf[r] += (float)p0[4 + r] + (float)p1[4 + r] + (float)p2[4 + r];
            }

            float hn_keep[4];
#pragma unroll
            for (int r = 0; r < 4; ++r) {
                int b = b0 + mi * 16 + (lane >> 4) * 4 + r;
                float iv = 1.0f / (1.0f + __expf(-(ci[r] + pix[r] + bi_s)));
                float fv = 1.0f / (1.0f + __expf(-(cf[r] + pfx[r] + bf_s)));
                float z = iv * pc[r] + fv * hprev[r];
                float hn = 1.0f - 2.0f / (__expf(2.0f * z) + 1.0f);   // tanh(z)
                hprev[r] = hn;
                hn_keep[r] = hn;
                _Float16 hn16 = (_Float16)hn;
                LLC_ST2(hnxt + (size_t)b * NH + jj, hn16);            // -> LLC
            }
            wait_vm0();        // drain h stores + canary re-arms (r5 lesson)
            __syncthreads();   // all owner waves complete at LLC
            if (tid == 0) LLC_ST4(hflags_g + js, (unsigned)(t + 1));

            // Off-critical-path: out stores + proj prefetch for next step.
#pragma unroll
            for (int r = 0; r < 4; ++r) {
                int b = b0 + mi * 16 + (lane >> 4) * 4 + r;
                out[(size_t)t * (BATCH * NH) + (size_t)b * NH + jj] = hn_keep[r];
                if (t == T_SEQ - 1)
                    out[(size_t)T_SEQ * (BATCH * NH) + (size_t)b * NH + jj] = hn_keep[r];
            }
            if (s + 1 < nsteps) {
#pragma unroll
                for (int r = 0; r < 4; ++r) {
                    int b = b0 + mi * 16 + (lane >> 4) * 4 + r;
                    size_t pbase = ((size_t)(s + 1) * 64 + b) * 6144 + jj;
                    pc[r] = (float)proj[pbase];
                    pix[r] = (float)proj[pbase + 2048];
                    pfx[r] = (float)proj[pbase + 4096];
                }
            }
        }
    }
}

// ---------------- host launch -----------------------------------------------
extern "C" void kernel_launch(void* const* d_in, const int* in_sizes, int n_in,
                              void* d_out, int out_size, void* d_ws, size_t ws_size,
                              hipStream_t stream) {
    const float* x = (const float*)d_in[0];
    const float* hidden = (const float*)d_in[1];
    const float* W_cx = (const float*)d_in[2];
    const float* W_ih = (const float*)d_in[3];
    const float* W_ix = (const float*)d_in[4];
    const float* W_fh = (const float*)d_in[5];
    const float* W_fx = (const float*)d_in[6];
    const float* b_i = (const float*)d_in[7];
    const float* b_f = (const float*)d_in[8];
    float* out = (float*)d_out;

    char* ws = (char*)d_ws;
    size_t off = 0;
    auto alloc = [&](size_t bytes) {
        char* p = ws + off;
        off += (bytes + 255) & ~(size_t)255;
        return p;
    };
    _Float16* Wp = (_Float16*)alloc((size_t)6144 * NH * 2);       // 24 MB
    _Float16* Wr = (_Float16*)alloc((size_t)2 * NH * NH * 2);     // 16 MB
    _Float16* hb0 = (_Float16*)alloc((size_t)BATCH * NH * 2);
    _Float16* hb1 = (_Float16*)alloc((size_t)BATCH * NH * 2);
    unsigned* hflags = (unsigned*)alloc(256);
    const size_t part_bytes = (size_t)2 * 2 * 32 * 3 * 8 * 512 * 2;  // 3 MB
    _Float16* part = (_Float16*)alloc(part_bytes);
    const size_t fixed = off;

    int chunk = 32;
    for (int c = T_SEQ; c >= 32; c >>= 1) {
        size_t need = fixed + (size_t)c * 64 * NH * 2 + (size_t)c * 64 * 6144 * 2 + 1024;
        if (need <= ws_size) { chunk = c; break; }
    }
    _Float16* xh = (_Float16*)alloc((size_t)chunk * 64 * NH * 2);
    _Float16* proj = (_Float16*)alloc((size_t)chunk * 64 * 6144 * 2);

    hipMemsetAsync(hflags, 0, 256, stream);
    hipMemsetAsync(part, 0xFF, part_bytes, stream);   // arm all canaries

    const long long wsz = (long long)NH * NH;
    cvt_f32_f16<<<2048, 256, 0, stream>>>(W_cx, Wp, wsz);
    cvt_f32_f16<<<2048, 256, 0, stream>>>(W_ix, Wp + wsz, wsz);
    cvt_f32_f16<<<2048, 256, 0, stream>>>(W_fx, Wp + 2 * wsz, wsz);
    cvt_f32_f16<<<2048, 256, 0, stream>>>(W_ih, Wr, wsz);
    cvt_f32_f16<<<2048, 256, 0, stream>>>(W_fh, Wr + wsz, wsz);
    cvt_f32_f16<<<128, 256, 0, stream>>>(hidden, hb0, (long long)BATCH * NH);

    const int nch = T_SEQ / chunk;
    for (int c = 0; c < nch; ++c) {
        const int t0 = c * chunk;
        const int M = chunk * 64;
        cvt_f32_f16<<<2048, 256, 0, stream>>>(x + (size_t)t0 * 64 * NH, xh, (long long)M * NH);
        proj_gemm<<<dim3((M / 128) * 48), 256, 0, stream>>>(xh, Wp, proj, M);
        scan_kernel<<<256, 512, 163840, stream>>>(proj, Wr, hb0, hb1, b_i, b_f,
                                                  out, hflags, part, t0, chunk);
    }
}